// Round 1
// 350.515 us; speedup vs baseline: 1.0781x; 1.0781x over previous
//
#include <hip/hip_runtime.h>

// OTTT single step:
//   u_pre  = sig_tau * u + x @ W + b
//   s      = (u_pre >= 1.0)
//   u_new  = u_pre - s
//   a_hat' = sig_tau * a_hat + x
// Outputs concatenated: [s (8192) | u_new (8192) | a_hat_new (8192)], f32.
//
// HBM-bound GEMV: W = 256 MiB f32 read dominates (~43 us floor at 6.3 TB/s).
// Split-K partials in d_ws, deterministic per-column reduction in finalize
// (no atomics so the spike comparison is reproducible).
//
// R2 changes (this round):
//  - W loads are nontemporal (pure 256 MiB stream, zero reuse) so the 8 MiB
//    partial buffer stays L2/L3-resident for finalize.
//  - finalize rewritten: 64 blocks x 256 threads, 8 chunk-groups x 32 chunks
//    per thread on float4 columns + LDS tree, instead of 32 blocks with a
//    serial 256-deep fold per thread (~6-8 us -> ~2-3 us, latency-bound).
//  - GEMV fold order and chunking unchanged -> bit-identical partials.

#define IN_DIM     8192
#define OUT_DIM    8192
#define SIG_TAU    0.8807970779778823f   // sigmoid(2.0)
#define V_TH       1.0f
#define CHUNK_ROWS 32
#define NCHUNKS    (IN_DIM / CHUNK_ROWS)   // 256

typedef float f4 __attribute__((ext_vector_type(4)));

// grid = (8, 256). Each thread owns 4 consecutive output columns (float4)
// and accumulates over its chunk's 32 rows. W row stride = 2048 float4s.
__global__ __launch_bounds__(256, 4) void gemv_partial_u32(
    const float* __restrict__ W,
    const float* __restrict__ x,
    float* __restrict__ part)
{
    const int col4 = blockIdx.x * 256 + threadIdx.x;      // float4 column idx
    const int row0 = blockIdx.y * CHUNK_ROWS;

    __shared__ float xs[CHUNK_ROWS];
    if (threadIdx.x < CHUNK_ROWS) xs[threadIdx.x] = x[row0 + threadIdx.x];
    __syncthreads();

    const f4* Wp = (const f4*)W + (size_t)row0 * (OUT_DIM / 4) + col4;
    f4 acc = {0.f, 0.f, 0.f, 0.f};

    #pragma unroll
    for (int r = 0; r < CHUNK_ROWS; ++r) {
        // Nontemporal: W is streamed exactly once; don't evict partials.
        const f4 w = __builtin_nontemporal_load(&Wp[(size_t)r * (OUT_DIM / 4)]);
        const float xv = xs[r];
        acc.x = fmaf(xv, w.x, acc.x);
        acc.y = fmaf(xv, w.y, acc.y);
        acc.z = fmaf(xv, w.z, acc.z);
        acc.w = fmaf(xv, w.w, acc.w);
    }

    ((f4*)part)[(size_t)blockIdx.y * (OUT_DIM / 4) + col4] = acc;
}

// Fallback when ws_size can't hold NCHUNKS*OUT_DIM partials (runtime rows).
__global__ __launch_bounds__(256) void gemv_partial_gen(
    const float* __restrict__ W,
    const float* __restrict__ x,
    float* __restrict__ part,
    int chunk_rows)
{
    const int col4 = blockIdx.x * 256 + threadIdx.x;
    const int row0 = blockIdx.y * chunk_rows;

    extern __shared__ float xsg[];
    for (int t = threadIdx.x; t < chunk_rows; t += 256)
        xsg[t] = x[row0 + t];
    __syncthreads();

    const f4* Wp = (const f4*)W + (size_t)row0 * (OUT_DIM / 4) + col4;
    f4 acc = {0.f, 0.f, 0.f, 0.f};

    #pragma unroll 8
    for (int r = 0; r < chunk_rows; ++r) {
        const f4 w = __builtin_nontemporal_load(&Wp[(size_t)r * (OUT_DIM / 4)]);
        const float xv = xsg[r];
        acc.x = fmaf(xv, w.x, acc.x);
        acc.y = fmaf(xv, w.y, acc.y);
        acc.z = fmaf(xv, w.z, acc.z);
        acc.w = fmaf(xv, w.w, acc.w);
    }

    ((f4*)part)[(size_t)blockIdx.y * (OUT_DIM / 4) + col4] = acc;
}

// Fast finalize (main path, NCHUNKS=256 known at compile time).
// grid = OUT_DIM/128 = 64 blocks, 256 threads.
// Block owns 128 columns = 32 float4-columns. Thread t: float4-col = t&31,
// chunk-group = t>>5 (8 groups x 32 chunks). LDS tree over the 8 groups.
// Reduction order = left-fold of left-folded groups (reassociation only;
// absmax impact ~1e-7).
__global__ __launch_bounds__(256) void finalize_lif_fast(
    const float* __restrict__ part,
    const float* __restrict__ b,
    const float* __restrict__ u,
    const float* __restrict__ a_hat,
    const float* __restrict__ x,
    float* __restrict__ out)
{
    __shared__ f4 red[8][32];

    const int lc4 = threadIdx.x & 31;          // local float4 column
    const int grp = threadIdx.x >> 5;          // chunk group 0..7
    const int c4  = blockIdx.x * 32 + lc4;     // global float4 column

    const f4* P = (const f4*)part;
    f4 acc = {0.f, 0.f, 0.f, 0.f};

    #pragma unroll
    for (int k = 0; k < NCHUNKS / 8; ++k) {    // 32 chunks per group
        const f4 p = P[(size_t)(grp * (NCHUNKS / 8) + k) * (OUT_DIM / 4) + c4];
        acc.x += p.x; acc.y += p.y; acc.z += p.z; acc.w += p.w;
    }
    red[grp][lc4] = acc;
    __syncthreads();

    if (threadIdx.x < 32) {
        f4 sum = red[0][lc4];
        #pragma unroll
        for (int g = 1; g < 8; ++g) {
            const f4 r = red[g][lc4];
            sum.x += r.x; sum.y += r.y; sum.z += r.z; sum.w += r.w;
        }

        const f4 b4  = ((const f4*)b)[c4];
        const f4 u4  = ((const f4*)u)[c4];
        const f4 ah4 = ((const f4*)a_hat)[c4];
        const f4 x4  = ((const f4*)x)[c4];

        f4 s4, un4, an4;
        {
            const float up = fmaf(SIG_TAU, u4.x, sum.x + b4.x);
            s4.x = (up >= V_TH) ? 1.0f : 0.0f; un4.x = up - s4.x * V_TH;
            an4.x = fmaf(SIG_TAU, ah4.x, x4.x);
        }
        {
            const float up = fmaf(SIG_TAU, u4.y, sum.y + b4.y);
            s4.y = (up >= V_TH) ? 1.0f : 0.0f; un4.y = up - s4.y * V_TH;
            an4.y = fmaf(SIG_TAU, ah4.y, x4.y);
        }
        {
            const float up = fmaf(SIG_TAU, u4.z, sum.z + b4.z);
            s4.z = (up >= V_TH) ? 1.0f : 0.0f; un4.z = up - s4.z * V_TH;
            an4.z = fmaf(SIG_TAU, ah4.z, x4.z);
        }
        {
            const float up = fmaf(SIG_TAU, u4.w, sum.w + b4.w);
            s4.w = (up >= V_TH) ? 1.0f : 0.0f; un4.w = up - s4.w * V_TH;
            an4.w = fmaf(SIG_TAU, ah4.w, x4.w);
        }

        f4* o = (f4*)out;
        o[c4]                    = s4;
        o[(OUT_DIM / 4) + c4]    = un4;
        o[2 * (OUT_DIM / 4) + c4] = an4;
    }
}

// Generic finalize (fallback path, runtime nchunks).
__global__ __launch_bounds__(256) void finalize_lif(
    const float* __restrict__ part,
    const float* __restrict__ b,
    const float* __restrict__ u,
    const float* __restrict__ a_hat,
    const float* __restrict__ x,
    float* __restrict__ out,
    int nchunks)
{
    const int j = blockIdx.x * 256 + threadIdx.x;
    if (j >= OUT_DIM) return;

    float sum = 0.f;
    #pragma unroll 8
    for (int c = 0; c < nchunks; ++c)
        sum += part[(size_t)c * OUT_DIM + j];

    const float u_pre = fmaf(SIG_TAU, u[j], sum + b[j]);
    const float s = (u_pre >= V_TH) ? 1.0f : 0.0f;

    out[j]               = s;
    out[OUT_DIM + j]     = u_pre - s * V_TH;
    out[2 * OUT_DIM + j] = fmaf(SIG_TAU, a_hat[j], x[j]);
}

extern "C" void kernel_launch(void* const* d_in, const int* in_sizes, int n_in,
                              void* d_out, int out_size, void* d_ws, size_t ws_size,
                              hipStream_t stream)
{
    const float* W     = (const float*)d_in[0];
    const float* b     = (const float*)d_in[1];
    const float* u     = (const float*)d_in[2];
    const float* a_hat = (const float*)d_in[3];
    const float* x     = (const float*)d_in[4];
    float* out  = (float*)d_out;
    float* part = (float*)d_ws;

    if ((size_t)NCHUNKS * OUT_DIM * sizeof(float) <= ws_size) {
        dim3 grid(OUT_DIM / (4 * 256), NCHUNKS);
        gemv_partial_u32<<<grid, 256, 0, stream>>>(W, x, part);
        finalize_lif_fast<<<OUT_DIM / 128, 256, 0, stream>>>(part, b, u, a_hat, x, out);
    } else {
        int nchunks = 128;
        while (nchunks > 1 && (size_t)nchunks * OUT_DIM * sizeof(float) > ws_size)
            nchunks >>= 1;
        const int chunk_rows = IN_DIM / nchunks;
        dim3 grid(OUT_DIM / (4 * 256), nchunks);
        gemv_partial_gen<<<grid, 256, chunk_rows * sizeof(float), stream>>>(W, x, part, chunk_rows);
        finalize_lif<<<OUT_DIM / 256, 256, 0, stream>>>(part, b, u, a_hat, x, out, nchunks);
    }
}

// Round 2
// 347.074 us; speedup vs baseline: 1.0888x; 1.0099x over previous
//
#include <hip/hip_runtime.h>

// OTTT single step:
//   u_pre  = sig_tau * u + x @ W + b
//   s      = (u_pre >= 1.0)
//   u_new  = u_pre - s
//   a_hat' = sig_tau * a_hat + x
// Outputs concatenated: [s (8192) | u_new (8192) | a_hat_new (8192)], f32.
//
// HBM-bound GEMV: W = 256 MiB f32 read dominates (~43 us floor at 6.7 TB/s
// achieved-fill BW). Split-K partials in d_ws, deterministic per-column
// reduction in finalize (no atomics -> reproducible spike comparison).
//
// R3 changes (this round):
//  - gemv thread-coarsening x2: each thread owns TWO float4 columns
//    (col4, col4+256). Halves address/LDS-broadcast overhead per load,
//    doubles per-wave memory-level parallelism. grid (4,256)=1024 blocks.
//  - dropped the min-waves launch_bounds arg on gemv (VGPR cap 128 -> 256)
//    so the 64 NT loads/thread can pipeline deeper.
//  - Per-column fold order, chunking, and finalize are UNCHANGED ->
//    outputs bit-identical to R2 (absmax must stay 0.00390625).

#define IN_DIM     8192
#define OUT_DIM    8192
#define SIG_TAU    0.8807970779778823f   // sigmoid(2.0)
#define V_TH       1.0f
#define CHUNK_ROWS 32
#define NCHUNKS    (IN_DIM / CHUNK_ROWS)   // 256

typedef float f4 __attribute__((ext_vector_type(4)));

// grid = (4, 256). Each thread owns 2 float4 columns (t and t+256 within the
// block's 512-f4 stripe) and accumulates over its chunk's 32 rows.
// W row stride = 2048 float4s.
__global__ __launch_bounds__(256) void gemv_partial_u32(
    const float* __restrict__ W,
    const float* __restrict__ x,
    float* __restrict__ part)
{
    const int col4 = blockIdx.x * 512 + threadIdx.x;      // first float4 col
    const int row0 = blockIdx.y * CHUNK_ROWS;

    __shared__ float xs[CHUNK_ROWS];
    if (threadIdx.x < CHUNK_ROWS) xs[threadIdx.x] = x[row0 + threadIdx.x];
    __syncthreads();

    const f4* Wp = (const f4*)W + (size_t)row0 * (OUT_DIM / 4) + col4;
    f4 a0 = {0.f, 0.f, 0.f, 0.f};
    f4 a1 = {0.f, 0.f, 0.f, 0.f};

    #pragma unroll
    for (int r = 0; r < CHUNK_ROWS; ++r) {
        // Nontemporal: W is streamed exactly once; don't evict partials.
        const f4 w0 = __builtin_nontemporal_load(&Wp[(size_t)r * (OUT_DIM / 4)]);
        const f4 w1 = __builtin_nontemporal_load(&Wp[(size_t)r * (OUT_DIM / 4) + 256]);
        const float xv = xs[r];
        a0.x = fmaf(xv, w0.x, a0.x);
        a0.y = fmaf(xv, w0.y, a0.y);
        a0.z = fmaf(xv, w0.z, a0.z);
        a0.w = fmaf(xv, w0.w, a0.w);
        a1.x = fmaf(xv, w1.x, a1.x);
        a1.y = fmaf(xv, w1.y, a1.y);
        a1.z = fmaf(xv, w1.z, a1.z);
        a1.w = fmaf(xv, w1.w, a1.w);
    }

    f4* P = (f4*)part + (size_t)blockIdx.y * (OUT_DIM / 4) + col4;
    P[0]   = a0;
    P[256] = a1;
}

// Fallback when ws_size can't hold NCHUNKS*OUT_DIM partials (runtime rows).
__global__ __launch_bounds__(256) void gemv_partial_gen(
    const float* __restrict__ W,
    const float* __restrict__ x,
    float* __restrict__ part,
    int chunk_rows)
{
    const int col4 = blockIdx.x * 256 + threadIdx.x;
    const int row0 = blockIdx.y * chunk_rows;

    extern __shared__ float xsg[];
    for (int t = threadIdx.x; t < chunk_rows; t += 256)
        xsg[t] = x[row0 + t];
    __syncthreads();

    const f4* Wp = (const f4*)W + (size_t)row0 * (OUT_DIM / 4) + col4;
    f4 acc = {0.f, 0.f, 0.f, 0.f};

    #pragma unroll 8
    for (int r = 0; r < chunk_rows; ++r) {
        const f4 w = __builtin_nontemporal_load(&Wp[(size_t)r * (OUT_DIM / 4)]);
        const float xv = xsg[r];
        acc.x = fmaf(xv, w.x, acc.x);
        acc.y = fmaf(xv, w.y, acc.y);
        acc.z = fmaf(xv, w.z, acc.z);
        acc.w = fmaf(xv, w.w, acc.w);
    }

    ((f4*)part)[(size_t)blockIdx.y * (OUT_DIM / 4) + col4] = acc;
}

// Fast finalize (main path, NCHUNKS=256 known at compile time).
// grid = OUT_DIM/128 = 64 blocks, 256 threads.
// Block owns 128 columns = 32 float4-columns. Thread t: float4-col = t&31,
// chunk-group = t>>5 (8 groups x 32 chunks). LDS tree over the 8 groups.
__global__ __launch_bounds__(256) void finalize_lif_fast(
    const float* __restrict__ part,
    const float* __restrict__ b,
    const float* __restrict__ u,
    const float* __restrict__ a_hat,
    const float* __restrict__ x,
    float* __restrict__ out)
{
    __shared__ f4 red[8][32];

    const int lc4 = threadIdx.x & 31;          // local float4 column
    const int grp = threadIdx.x >> 5;          // chunk group 0..7
    const int c4  = blockIdx.x * 32 + lc4;     // global float4 column

    const f4* P = (const f4*)part;
    f4 acc = {0.f, 0.f, 0.f, 0.f};

    #pragma unroll
    for (int k = 0; k < NCHUNKS / 8; ++k) {    // 32 chunks per group
        const f4 p = P[(size_t)(grp * (NCHUNKS / 8) + k) * (OUT_DIM / 4) + c4];
        acc.x += p.x; acc.y += p.y; acc.z += p.z; acc.w += p.w;
    }
    red[grp][lc4] = acc;
    __syncthreads();

    if (threadIdx.x < 32) {
        f4 sum = red[0][lc4];
        #pragma unroll
        for (int g = 1; g < 8; ++g) {
            const f4 r = red[g][lc4];
            sum.x += r.x; sum.y += r.y; sum.z += r.z; sum.w += r.w;
        }

        const f4 b4  = ((const f4*)b)[c4];
        const f4 u4  = ((const f4*)u)[c4];
        const f4 ah4 = ((const f4*)a_hat)[c4];
        const f4 x4  = ((const f4*)x)[c4];

        f4 s4, un4, an4;
        {
            const float up = fmaf(SIG_TAU, u4.x, sum.x + b4.x);
            s4.x = (up >= V_TH) ? 1.0f : 0.0f; un4.x = up - s4.x * V_TH;
            an4.x = fmaf(SIG_TAU, ah4.x, x4.x);
        }
        {
            const float up = fmaf(SIG_TAU, u4.y, sum.y + b4.y);
            s4.y = (up >= V_TH) ? 1.0f : 0.0f; un4.y = up - s4.y * V_TH;
            an4.y = fmaf(SIG_TAU, ah4.y, x4.y);
        }
        {
            const float up = fmaf(SIG_TAU, u4.z, sum.z + b4.z);
            s4.z = (up >= V_TH) ? 1.0f : 0.0f; un4.z = up - s4.z * V_TH;
            an4.z = fmaf(SIG_TAU, ah4.z, x4.z);
        }
        {
            const float up = fmaf(SIG_TAU, u4.w, sum.w + b4.w);
            s4.w = (up >= V_TH) ? 1.0f : 0.0f; un4.w = up - s4.w * V_TH;
            an4.w = fmaf(SIG_TAU, ah4.w, x4.w);
        }

        f4* o = (f4*)out;
        o[c4]                     = s4;
        o[(OUT_DIM / 4) + c4]     = un4;
        o[2 * (OUT_DIM / 4) + c4] = an4;
    }
}

// Generic finalize (fallback path, runtime nchunks).
__global__ __launch_bounds__(256) void finalize_lif(
    const float* __restrict__ part,
    const float* __restrict__ b,
    const float* __restrict__ u,
    const float* __restrict__ a_hat,
    const float* __restrict__ x,
    float* __restrict__ out,
    int nchunks)
{
    const int j = blockIdx.x * 256 + threadIdx.x;
    if (j >= OUT_DIM) return;

    float sum = 0.f;
    #pragma unroll 8
    for (int c = 0; c < nchunks; ++c)
        sum += part[(size_t)c * OUT_DIM + j];

    const float u_pre = fmaf(SIG_TAU, u[j], sum + b[j]);
    const float s = (u_pre >= V_TH) ? 1.0f : 0.0f;

    out[j]               = s;
    out[OUT_DIM + j]     = u_pre - s * V_TH;
    out[2 * OUT_DIM + j] = fmaf(SIG_TAU, a_hat[j], x[j]);
}

extern "C" void kernel_launch(void* const* d_in, const int* in_sizes, int n_in,
                              void* d_out, int out_size, void* d_ws, size_t ws_size,
                              hipStream_t stream)
{
    const float* W     = (const float*)d_in[0];
    const float* b     = (const float*)d_in[1];
    const float* u     = (const float*)d_in[2];
    const float* a_hat = (const float*)d_in[3];
    const float* x     = (const float*)d_in[4];
    float* out  = (float*)d_out;
    float* part = (float*)d_ws;

    if ((size_t)NCHUNKS * OUT_DIM * sizeof(float) <= ws_size) {
        dim3 grid(OUT_DIM / (4 * 512), NCHUNKS);   // (4, 256)
        gemv_partial_u32<<<grid, 256, 0, stream>>>(W, x, part);
        finalize_lif_fast<<<OUT_DIM / 128, 256, 0, stream>>>(part, b, u, a_hat, x, out);
    } else {
        int nchunks = 128;
        while (nchunks > 1 && (size_t)nchunks * OUT_DIM * sizeof(float) > ws_size)
            nchunks >>= 1;
        const int chunk_rows = IN_DIM / nchunks;
        dim3 grid(OUT_DIM / (4 * 256), nchunks);
        gemv_partial_gen<<<grid, 256, chunk_rows * sizeof(float), stream>>>(W, x, part, chunk_rows);
        finalize_lif<<<OUT_DIM / 256, 256, 0, stream>>>(part, b, u, a_hat, x, out, nchunks);
    }
}